// Round 9
// baseline (83.267 us; speedup 1.0000x reference)
//
#include <hip/hip_runtime.h>
#include <math.h>

constexpr int B = 2, C = 16, H = 128, W = 128;
constexpr int HW = H * W;

// xpad: [B,16,146,148]; orig (h,w) -> (h+9, w+9); pads zeroed by conv1
constexpr int XR = 146, XS = 148, XCH = XR * XS;
constexpr size_t XPAD_ELEMS = (size_t)B * C * XCH;          // 691,456

// ypad: [B,16,130,136]; orig (h,w) -> (h+1, w+4); pads zeroed by kpn19
constexpr int YR = 130, YS = 136, YCH = YR * YS;
constexpr size_t YPAD_ELEMS = (size_t)B * C * YCH;          // 565,760

__device__ __forceinline__ float4 ld4(const float* p) { return *(const float4*)p; }

// ===========================================================================
// kpn19 (round-7 structure, the fast variant): per-pixel 19x19 conv.
// Plain-HIP loads, two-row register double buffer, sched_barrier(0) fences.
// waves_per_eu(2,2) -> 256-VGPR budget so the ~220-VGPR live batch fits and
// the scheduler has no occupancy incentive to sink/spill the loads.
// Thread = 4 px x 1 ch, all 19 rows. Block = 8wq x 16c = 128 thr (32px,16ch).
// Grid = wb4 x h128 x b2 = 1024 blocks -> 4 blocks/CU, 8 waves/CU, one pass.
// ===========================================================================
#define KPN_LOAD(KBUF, XBUF, kh_)                                            \
  {                                                                          \
    const float* kp_ = kb + (size_t)((kh_) * 19) * HW;                       \
    _Pragma("unroll")                                                        \
    for (int kw_ = 0; kw_ < 19; ++kw_)                                       \
      KBUF[kw_] = ld4(kp_ + (size_t)kw_ * HW);                               \
    const float* xr_ = xb + (size_t)(kh_) * XS;                              \
    _Pragma("unroll")                                                        \
    for (int j_ = 0; j_ < 6; ++j_)                                           \
      XBUF[j_] = ld4(xr_ + 4 * j_);                                          \
  }                                                                          \
  __builtin_amdgcn_sched_barrier(0);

#define XCOMP(XB, I)                                                         \
  (((I) & 3) == 0 ? XB[(I) >> 2].x : ((I) & 3) == 1 ? XB[(I) >> 2].y         \
   : ((I) & 3) == 2 ? XB[(I) >> 2].z : XB[(I) >> 2].w)

#define KPN_COMP(KBUF, XBUF)                                                 \
  {                                                                          \
    _Pragma("unroll")                                                        \
    for (int kw_ = 0; kw_ < 19; ++kw_) {                                     \
      acc.x = fmaf(XCOMP(XBUF, kw_ + 0), KBUF[kw_].x, acc.x);                \
      acc.y = fmaf(XCOMP(XBUF, kw_ + 1), KBUF[kw_].y, acc.y);                \
      acc.z = fmaf(XCOMP(XBUF, kw_ + 2), KBUF[kw_].z, acc.z);                \
      acc.w = fmaf(XCOMP(XBUF, kw_ + 3), KBUF[kw_].w, acc.w);                \
    }                                                                        \
  }                                                                          \
  __builtin_amdgcn_sched_barrier(0);

__global__ __launch_bounds__(128) __attribute__((amdgpu_waves_per_eu(2, 2)))
void kpn19(const float* __restrict__ xpad,   // [B,16,146,148]
           const float* __restrict__ kern,   // [B,361,128,128]
           float* __restrict__ ypad)         // [B,16,130,136]
{
    int wq = threadIdx.x & 7;
    int c  = threadIdx.x >> 3;       // 0..15
    int blk = blockIdx.x;            // 1024 = wb4 x h128 x b2
    int wb = blk & 3;
    int h  = (blk >> 2) & 127;
    int b  = blk >> 9;
    int w0 = wb * 32 + wq * 4;

    // ---- ypad pad-zeroing (replaces the memset dispatch) ----
    // col pads of row h+1: wb==0 -> cols 0..3, wb==3 -> cols 132..135
    if ((wb == 0 || wb == 3) && threadIdx.x < 64) {
        int pl = threadIdx.x >> 2, i = threadIdx.x & 3;
        int col = (wb == 0) ? i : 132 + i;
        ypad[((size_t)(b * C + pl) * YR + (h + 1)) * YS + col] = 0.f;
    }
    // row pads (rows 0 and 129), split across the 4 wb blocks
    if (h == 0 || h == 127) {
        int r = (h == 0) ? 0 : 129;
        for (int f = threadIdx.x; f < 16 * 34; f += 128) {
            int pl = f / 34, col = wb * 34 + f % 34;
            ypad[((size_t)(b * C + pl) * YR + r) * YS + col] = 0.f;
        }
    }

    const float* kb = kern + (size_t)b * 361 * HW + (size_t)h * W + w0;
    const float* xb = xpad + (size_t)(b * C + c) * XCH + (size_t)h * XS + w0;

    float4 KA[19], KB[19], XA[6], XB[6];
    float4 acc = make_float4(0.f, 0.f, 0.f, 0.f);

    KPN_LOAD(KA, XA, 0);
    for (int rr = 0; rr < 9; ++rr) {
        KPN_LOAD(KB, XB, 2 * rr + 1);
        KPN_COMP(KA, XA);                // compiler inserts counted waits
        KPN_LOAD(KA, XA, 2 * rr + 2);
        KPN_COMP(KB, XB);
    }
    KPN_COMP(KA, XA);                    // row 18

    float* yp = ypad + ((size_t)(b * C + c) * YR + (h + 1)) * YS + (w0 + 4);
    *(float4*)yp = acc;
}

// ===========================================================================
// conv1: 3x3 conv (pad 1) + exact GELU -> xpad. Thread = 1 px x 2 oc.
// Block = 128 px x 2 oc-pairs; grid = ocq4 x h128 x b2 = 1024.
// Also zeroes this block's share of xpad pad cells.
// ===========================================================================
__global__ __launch_bounds__(256) void conv1_gelu(
    const float* __restrict__ in, const float* __restrict__ w1,
    const float* __restrict__ b1, float* __restrict__ xpad)
{
    __shared__ float ws[2304];
    __shared__ float bs[16];
    for (int i = threadIdx.x; i < 2304; i += 256) ws[i] = w1[i];
    if (threadIdx.x < 16) bs[threadIdx.x] = b1[threadIdx.x];
    __syncthreads();

    int px  = threadIdx.x & 127;
    int opg = threadIdx.x >> 7;          // wave-uniform
    int blk = blockIdx.x;                // 1024 = ocq4 x h128 x b2
    int ocq = blk & 3;
    int h   = (blk >> 2) & 127;
    int b   = blk >> 9;
    int oc0 = ocq * 4 + opg * 2;

    // ---- xpad pad-zeroing for the 4 planes this block owns ----
    // col pads of row h+9: cols 0..8 and 137..147 (20 cols) x 4 planes
    if (threadIdx.x < 80) {
        int j = threadIdx.x / 20, i = threadIdx.x % 20;
        int col = (i < 9) ? i : 128 + i;             // 137..147
        xpad[((size_t)(b * C + ocq * 4 + j) * XR + (h + 9)) * XS + col] = 0.f;
    }
    // row pads: rows 0..8 (h==0 blocks) / rows 137..145 (h==127 blocks)
    if (h == 0 || h == 127) {
        int r0 = (h == 0) ? 0 : 137;
        for (int f = threadIdx.x; f < 4 * 9 * XS; f += 256) {
            int j = f / (9 * XS), rem = f % (9 * XS);
            int r = r0 + rem / XS, col = rem % XS;
            xpad[((size_t)(b * C + ocq * 4 + j) * XR + r) * XS + col] = 0.f;
        }
    }

    const float* inb = in + (size_t)b * C * HW;
    bool hm = (h > 0), hp = (h < 127), wm = (px > 0), wp = (px < 127);

    float a0 = 0.f, a1 = 0.f;
    #pragma unroll
    for (int ic = 0; ic < 16; ++ic) {
        const float* p0 = inb + (size_t)ic * HW + (size_t)h * W + px;
        float t0 = (hm && wm) ? p0[-W - 1] : 0.f;
        float t1 = hm         ? p0[-W]     : 0.f;
        float t2 = (hm && wp) ? p0[-W + 1] : 0.f;
        float t3 = wm         ? p0[-1]     : 0.f;
        float t4 =              p0[0];
        float t5 = wp         ? p0[1]      : 0.f;
        float t6 = (hp && wm) ? p0[W - 1]  : 0.f;
        float t7 = hp         ? p0[W]      : 0.f;
        float t8 = (hp && wp) ? p0[W + 1]  : 0.f;
        #pragma unroll
        for (int j = 0; j < 2; ++j) {
            const float* wp9 = ws + (oc0 + j) * 144 + ic * 9;
            float s = fmaf(wp9[0], t0, fmaf(wp9[1], t1, fmaf(wp9[2], t2,
                      fmaf(wp9[3], t3, fmaf(wp9[4], t4, fmaf(wp9[5], t5,
                      fmaf(wp9[6], t6, fmaf(wp9[7], t7, wp9[8] * t8))))))));
            if (j == 0) a0 += s; else a1 += s;
        }
    }

    float* xp = xpad + ((size_t)(b * C + oc0) * XR + (h + 9)) * XS + (px + 9);
    float v;
    v = a0 + bs[oc0 + 0]; xp[0]   = 0.5f * v * (1.0f + erff(v * 0.70710678f));
    v = a1 + bs[oc0 + 1]; xp[XCH] = 0.5f * v * (1.0f + erff(v * 0.70710678f));
}

// ===========================================================================
// conv2: 3x3 conv (pad 1) + sigmoid -> out. Padded y input -> unconditional
// taps. Thread = 1 px x 2 oc; grid = ocq4 x h128 x b2 = 1024.
// ===========================================================================
__global__ __launch_bounds__(256) void conv2_sig(
    const float* __restrict__ ypad, const float* __restrict__ w2,
    const float* __restrict__ b2, float* __restrict__ out)
{
    __shared__ float ws[2304];
    __shared__ float bs[16];
    for (int i = threadIdx.x; i < 2304; i += 256) ws[i] = w2[i];
    if (threadIdx.x < 16) bs[threadIdx.x] = b2[threadIdx.x];
    __syncthreads();

    int px  = threadIdx.x & 127;
    int opg = threadIdx.x >> 7;
    int blk = blockIdx.x;                // 1024 = ocq4 x h128 x b2
    int ocq = blk & 3;
    int h   = (blk >> 2) & 127;
    int b   = blk >> 9;
    int oc0 = ocq * 4 + opg * 2;

    float a0 = 0.f, a1 = 0.f;
    #pragma unroll
    for (int ic = 0; ic < 16; ++ic) {
        const float* p0 = ypad + ((size_t)(b * C + ic) * YR + (h + 1)) * YS + (px + 4);
        float t0 = p0[-YS - 1], t1 = p0[-YS], t2 = p0[-YS + 1];
        float t3 = p0[-1],      t4 = p0[0],   t5 = p0[1];
        float t6 = p0[YS - 1],  t7 = p0[YS],  t8 = p0[YS + 1];
        #pragma unroll
        for (int j = 0; j < 2; ++j) {
            const float* wp9 = ws + (oc0 + j) * 144 + ic * 9;
            float s = fmaf(wp9[0], t0, fmaf(wp9[1], t1, fmaf(wp9[2], t2,
                      fmaf(wp9[3], t3, fmaf(wp9[4], t4, fmaf(wp9[5], t5,
                      fmaf(wp9[6], t6, fmaf(wp9[7], t7, wp9[8] * t8))))))));
            if (j == 0) a0 += s; else a1 += s;
        }
    }

    float* op = out + ((size_t)(b * C + oc0) * H + h) * W + px;
    float v;
    v = a0 + bs[oc0 + 0]; op[0]  = 1.0f / (1.0f + expf(-v));
    v = a1 + bs[oc0 + 1]; op[HW] = 1.0f / (1.0f + expf(-v));
}

// ---------------------------------------------------------------------------
extern "C" void kernel_launch(void* const* d_in, const int* in_sizes, int n_in,
                              void* d_out, int out_size, void* d_ws, size_t ws_size,
                              hipStream_t stream)
{
    const float* input  = (const float*)d_in[0];
    const float* kernel = (const float*)d_in[1];
    const float* w1     = (const float*)d_in[2];
    const float* b1     = (const float*)d_in[3];
    const float* w2     = (const float*)d_in[4];
    const float* b2     = (const float*)d_in[5];
    float* out = (float*)d_out;

    float* xpad = (float*)d_ws;
    float* ypad = xpad + XPAD_ELEMS;

    conv1_gelu<<<1024, 256, 0, stream>>>(input, w1, b1, xpad);
    kpn19<<<1024, 128, 0, stream>>>(xpad, kernel, ypad);
    conv2_sig<<<1024, 256, 0, stream>>>(ypad, w2, b2, out);
}